// Round 4
// baseline (113.065 us; speedup 1.0000x reference)
//
#include <hip/hip_runtime.h>
#include <math.h>

#define HW 512
#define NB 16
#define TX 32           // tile width
#define TY 32           // tile height
#define LDSW 40         // TX + 8 (4-col halo left, 4 right; float4-aligned)
#define LDSH 38         // TY + 6
#define N_PIX (NB * HW * HW)    // 4194304
#define NBLK (16 * 16 * NB)     // 4096 phase-1 blocks (single-wave each)

using f32x4 = __attribute__((ext_vector_type(4))) float;

// Force a float into an SGPR (uniform across wave).
__device__ __forceinline__ float sgpr_f(float v) {
    return __uint_as_float(__builtin_amdgcn_readfirstlane(__float_as_uint(v)));
}

// Phase 1: 32x32 tile per SINGLE-WAVE block; thread = 4 cols x 4 rows.
// Rationale (round-3 counters): 64x64/4-wave blocks ran at 22% occupancy,
// 23% VALUBusy, 17% HBM -- pure latency-bound. Single-wave blocks remove all
// inter-wave barrier coupling; 4096 blocks give ~16 independent waves/CU so
// the scheduler can cover every ds_read chain with other waves' VALU work.
// dif via identity: sum w*relu(v-c) = sum w*max(v,c) - c*sum(w)  (2 ops/tap).
__global__ __launch_bounds__(64, 4) void li_phase1(
    const float* __restrict__ x, const float* __restrict__ kw,
    float* __restrict__ out_ratio, float* __restrict__ out_avg,
    float* __restrict__ out_dif, float* __restrict__ partials)
{
    __shared__ float tile[LDSH * LDSW];   // 6080 B

    const int tid = threadIdx.x;          // 0..63 (one wave)
    const int bx = blockIdx.x, by = blockIdx.y, b = blockIdx.z;
    const int x0 = bx * TX, y0 = by * TY;
    const float* xb = x + (size_t)b * (HW * HW);

    // 49 weights pinned to SGPRs; W = sum of all weights (center weight is 0).
    float w[49];
    float W = 0.f;
#pragma unroll
    for (int i = 0; i < 49; i++) { w[i] = sgpr_f(kw[i]); W += w[i]; }

    // Stage 38 x 40 tile with zero halo, float4 granularity (380 float4s).
    for (int idx = tid; idx < LDSH * (LDSW / 4); idx += 64) {
        int r = idx / (LDSW / 4);
        int c4 = idx - r * (LDSW / 4);
        int gy = y0 - 3 + r;
        int gx = x0 - 4 + c4 * 4;
        float4 v = make_float4(0.f, 0.f, 0.f, 0.f);
        if ((unsigned)gy < HW && (unsigned)gx < HW)
            v = *(const float4*)(xb + gy * HW + gx);
        *(float4*)&tile[r * LDSW + c4 * 4] = v;
    }
    __syncthreads();   // single-wave: effectively just a waitcnt

    const int cx = tid & 7;          // column group: output cols 4cx..4cx+3
    const int cy = tid >> 3;         // row group:    output rows 4cy..4cy+3
    const int colw = 4 * cx;         // LDS word col of v[0] (= tile col - 4)
    const int row0 = 4 * cy;         // first streamed LDS row

    // Centers: 4 aligned float4 loads (LDS cols colw+4..colw+7 = own columns).
    float cen[16];
#pragma unroll
    for (int p = 0; p < 4; p++) {
        float4 c4v = *(const float4*)&tile[(row0 + 3 + p) * LDSW + colw + 4];
        cen[p*4+0] = c4v.x; cen[p*4+1] = c4v.y; cen[p*4+2] = c4v.z; cen[p*4+3] = c4v.w;
    }

    float dif[16], bsum[16];
#pragma unroll
    for (int k = 0; k < 16; k++) { dif[k] = 0.f; bsum[k] = 0.f; }

    // Stream 10 window rows; 3 aligned b128 per row, compiler-scheduled
    // (no barriers anywhere -> scheduler can hoist next row's reads freely).
#pragma unroll
    for (int r = 0; r < 10; r++) {
        const float* base = &tile[(row0 + r) * LDSW + colw];
        float4 q0 = *(const float4*)base;
        float4 q1 = *(const float4*)(base + 4);
        float4 q2 = *(const float4*)(base + 8);
        float v[12] = {q0.x, q0.y, q0.z, q0.w,
                       q1.x, q1.y, q1.z, q1.w,
                       q2.x, q2.y, q2.z, q2.w};

        // Sliding 7-wide row sums for the 4 output columns.
        float s0 = ((v[1] + v[2]) + (v[3] + v[4])) + ((v[5] + v[6]) + v[7]);
        float s1 = s0 + (v[8]  - v[1]);
        float s2 = s1 + (v[9]  - v[2]);
        float s3 = s2 + (v[10] - v[3]);

#pragma unroll
        for (int p = 0; p < 4; p++) {
            const int di = r - p;              // window row index 0..6
            if (di < 0 || di >= 7) continue;   // compile-time resolved
            bsum[p*4+0] += s0; bsum[p*4+1] += s1;
            bsum[p*4+2] += s2; bsum[p*4+3] += s3;
#pragma unroll
            for (int dj = 0; dj < 7; dj++) {
                if (di == 3 && dj == 3) continue;   // center weight == 0
                const float wv = w[di*7+dj];
#pragma unroll
                for (int j = 0; j < 4; j++)
                    dif[p*4+j] = fmaf(wv, fmaxf(v[1+j+dj], cen[p*4+j]), dif[p*4+j]);
            }
        }
    }

    // Epilogue: plain float4 stores (full-line, write-combined in L2).
    const size_t gbase = (size_t)b * (HW * HW) + (size_t)(y0 + row0) * HW + x0 + colw;
    float ss = 0.f;
#pragma unroll
    for (int p = 0; p < 4; p++) {
        float av[4], dv[4], rv[4];
#pragma unroll
        for (int j = 0; j < 4; j++) {
            const int k = p*4+j;
            av[j] = __expf(-bsum[k] * (1.0f / 49.0f));
            dv[j] = fmaf(-W, cen[k], dif[k]);            // subtract c*sum(w)
            const float spv = 0.1f * av[j] + 0.9f * dv[j];  // > 0 always
            rv[j] = cen[k] * __builtin_amdgcn_rcpf(spv);
            ss = fmaf(spv, spv, ss);
        }
        const size_t gi = gbase + (size_t)p * HW;
        *(f32x4*)(out_avg + gi)   = (f32x4){av[0], av[1], av[2], av[3]};
        *(f32x4*)(out_dif + gi)   = (f32x4){dv[0], dv[1], dv[2], dv[3]};
        *(f32x4*)(out_ratio + gi) = (f32x4){rv[0], rv[1], rv[2], rv[3]};
    }

    // Wave reduction of ss -> partials[bid] (single wave: no LDS needed).
#pragma unroll
    for (int off = 32; off > 0; off >>= 1)
        ss += __shfl_down(ss, off, 64);
    if (tid == 0)
        partials[bx + 16 * (by + 16 * b)] = ss;
}

// Phase 2 (reduce fused): each block sums the 4096 partials itself (16 KB,
// L2-resident), then masks its 4096-element slice: mask = (ratio > 1/sqrt(ss)).
__global__ __launch_bounds__(256) void li_phase2(
    const float* __restrict__ partials, float* __restrict__ io)
{
    __shared__ float wsum[4];
    __shared__ float s_inv;
    const int tid = threadIdx.x;

    float s = 0.f;
#pragma unroll
    for (int i = 0; i < NBLK / 256; i++)
        s += partials[tid + i * 256];
#pragma unroll
    for (int off = 32; off > 0; off >>= 1)
        s += __shfl_down(s, off, 64);
    if ((tid & 63) == 0) wsum[tid >> 6] = s;
    __syncthreads();
    if (tid == 0)
        s_inv = 1.0f / sqrtf((wsum[0] + wsum[1]) + (wsum[2] + wsum[3]));
    __syncthreads();

    const float inv = s_inv;
    const int base = blockIdx.x * 4096 + tid * 4;
#pragma unroll
    for (int k = 0; k < 4; k++) {
        const int i = base + k * 1024;
        float4 r = *(const float4*)(io + i);
        float4 m;
        m.x = (r.x > inv) ? 1.f : 0.f;
        m.y = (r.y > inv) ? 1.f : 0.f;
        m.z = (r.z > inv) ? 1.f : 0.f;
        m.w = (r.w > inv) ? 1.f : 0.f;
        *(float4*)(io + i) = m;
    }
}

extern "C" void kernel_launch(void* const* d_in, const int* in_sizes, int n_in,
                              void* d_out, int out_size, void* d_ws, size_t ws_size,
                              hipStream_t stream) {
    const float* x  = (const float*)d_in[0];
    const float* kw = (const float*)d_in[1];
    float* out   = (float*)d_out;
    float* ratio = out;                       // becomes mask after phase 2
    float* avg   = out + N_PIX;
    float* dif   = out + 2 * (size_t)N_PIX;
    float* ws    = (float*)d_ws;              // [0,NBLK): partials (fully written)

    dim3 g(HW / TX, HW / TY, NB);   // 16 x 16 x 16 = 4096 single-wave blocks
    li_phase1<<<g, 64, 0, stream>>>(x, kw, ratio, avg, dif, ws);
    li_phase2<<<N_PIX / 4096, 256, 0, stream>>>(ws, ratio);
}

// Round 6
// 100.816 us; speedup vs baseline: 1.1215x; 1.1215x over previous
//
#include <hip/hip_runtime.h>
#include <math.h>

#define HW 512
#define NB 16
#define TX 64           // tile width  (8x8x16 grid of 256-thread blocks)
#define TY 64           // tile height
#define N_PIX (NB * HW * HW)    // 4194304
#define NBLK (8 * 8 * NB)       // 1024 phase-1 blocks

using f32x4 = __attribute__((ext_vector_type(4))) float;

// Force a float into an SGPR (uniform across wave).
__device__ __forceinline__ float sgpr_f(float v) {
    return __uint_as_float(__builtin_amdgcn_readfirstlane(__float_as_uint(v)));
}

// Guarded window load: window float4s are 4-col-aligned and HW%4==0, so each
// float4 is either fully inside [0,HW) or fully outside -> one compare total.
__device__ __forceinline__ float4 ld4g(const float* rowp, int c0, bool vrow) {
    if (vrow && (unsigned)c0 <= (unsigned)(HW - 4))
        return *(const float4*)(rowp + c0);
    return make_float4(0.f, 0.f, 0.f, 0.f);
}

// Per-thread 4x4 patch, window streamed from GLOBAL memory (no LDS, no
// barrier): 30 coalesced aligned dwordx4 loads per thread; the input is
// 16 MiB (L2/L3-resident), so halo re-reads never touch HBM (round-3
// counters: FETCH ~= input size despite staging amplification).
// dif via identity: sum w*relu(v-c) = sum w*max(v,c) - c*sum(w)  (2 ops/tap).
template<bool EDGE>
__device__ __forceinline__ void tile_compute(
    const float* __restrict__ xb, const float* __restrict__ w,
    int x0, int y0, int colw, int row0,
    float* __restrict__ cen, float* __restrict__ dif, float* __restrict__ bsum)
{
    const int c0 = x0 + colw - 4;          // global col of v[0] (4-aligned)

    // Centers: always in-range (they ARE the output pixels).
#pragma unroll
    for (int p = 0; p < 4; p++) {
        const float* rowp = xb + (y0 + row0 + p) * HW;
        float4 c4 = *(const float4*)(rowp + c0 + 4);
        cen[p*4+0] = c4.x; cen[p*4+1] = c4.y; cen[p*4+2] = c4.z; cen[p*4+3] = c4.w;
    }

#pragma unroll
    for (int k = 0; k < 16; k++) { dif[k] = 0.f; bsum[k] = 0.f; }

    // Stream 10 window rows; 3 independent 16B loads per row.
#pragma unroll
    for (int r = 0; r < 10; r++) {
        const int gy = y0 + row0 + r - 3;
        const float* rowp = xb + gy * HW;   // not dereferenced when row invalid
        float4 q0, q1, q2;
        if (EDGE) {
            const bool vrow = (unsigned)gy < (unsigned)HW;
            q0 = ld4g(rowp, c0,     vrow);
            q1 = ld4g(rowp, c0 + 4, vrow);
            q2 = ld4g(rowp, c0 + 8, vrow);
        } else {
            q0 = *(const float4*)(rowp + c0);
            q1 = *(const float4*)(rowp + c0 + 4);
            q2 = *(const float4*)(rowp + c0 + 8);
        }
        float v[12] = {q0.x, q0.y, q0.z, q0.w,
                       q1.x, q1.y, q1.z, q1.w,
                       q2.x, q2.y, q2.z, q2.w};

        // Sliding 7-wide row sums for the 4 output columns.
        float s0 = ((v[1] + v[2]) + (v[3] + v[4])) + ((v[5] + v[6]) + v[7]);
        float s1 = s0 + (v[8]  - v[1]);
        float s2 = s1 + (v[9]  - v[2]);
        float s3 = s2 + (v[10] - v[3]);

#pragma unroll
        for (int p = 0; p < 4; p++) {
            const int di = r - p;              // window row index 0..6
            if (di < 0 || di >= 7) continue;   // compile-time resolved
            bsum[p*4+0] += s0; bsum[p*4+1] += s1;
            bsum[p*4+2] += s2; bsum[p*4+3] += s3;
#pragma unroll
            for (int dj = 0; dj < 7; dj++) {
                if (di == 3 && dj == 3) continue;   // center weight == 0
                const float wv = w[di*7+dj];
#pragma unroll
                for (int j = 0; j < 4; j++)
                    dif[p*4+j] = fmaf(wv, fmaxf(v[1+j+dj], cen[p*4+j]), dif[p*4+j]);
            }
        }
    }
}

__global__ __launch_bounds__(256, 2) void li_phase1(
    const float* __restrict__ x, const float* __restrict__ kw,
    float* __restrict__ out_ratio, float* __restrict__ out_avg,
    float* __restrict__ out_dif, float* __restrict__ partials)
{
    __shared__ float wsum[4];   // 16 B: cross-wave reduce only

    const int tid = threadIdx.x;
    const int bx = blockIdx.x, by = blockIdx.y, b = blockIdx.z;
    const int x0 = bx * TX, y0 = by * TY;
    const float* xb = x + (size_t)b * (HW * HW);

    // 49 weights pinned to SGPRs; W = sum of all weights (center weight is 0).
    float w[49];
    float W = 0.f;
#pragma unroll
    for (int i = 0; i < 49; i++) { w[i] = sgpr_f(kw[i]); W += w[i]; }

    const int cx = tid & 15;         // column group: output cols 4cx..4cx+3
    const int cy = tid >> 4;         // row group:    output rows 4cy..4cy+3
    const int colw = 4 * cx;
    const int row0 = 4 * cy;

    float cen[16], dif[16], bsum[16];
    const bool edge = (bx == 0) | (bx == 7) | (by == 0) | (by == 7);
    if (edge)
        tile_compute<true >(xb, w, x0, y0, colw, row0, cen, dif, bsum);
    else
        tile_compute<false>(xb, w, x0, y0, colw, row0, cen, dif, bsum);

    // Epilogue: plain float4 stores (full-line, write-combined in L2).
    const size_t gbase = (size_t)b * (HW * HW) + (size_t)(y0 + row0) * HW + x0 + colw;
    float ss = 0.f;
#pragma unroll
    for (int p = 0; p < 4; p++) {
        float av[4], dv[4], rv[4];
#pragma unroll
        for (int j = 0; j < 4; j++) {
            const int k = p*4+j;
            av[j] = __expf(-bsum[k] * (1.0f / 49.0f));
            dv[j] = fmaf(-W, cen[k], dif[k]);               // subtract c*sum(w)
            const float spv = 0.1f * av[j] + 0.9f * dv[j];  // > 0 always
            rv[j] = cen[k] * __builtin_amdgcn_rcpf(spv);
            ss = fmaf(spv, spv, ss);
        }
        const size_t gi = gbase + (size_t)p * HW;
        *(f32x4*)(out_avg + gi)   = (f32x4){av[0], av[1], av[2], av[3]};
        *(f32x4*)(out_dif + gi)   = (f32x4){dv[0], dv[1], dv[2], dv[3]};
        *(f32x4*)(out_ratio + gi) = (f32x4){rv[0], rv[1], rv[2], rv[3]};
    }

    // Block reduction of ss -> partials[bid].
#pragma unroll
    for (int off = 32; off > 0; off >>= 1)
        ss += __shfl_down(ss, off, 64);
    if ((tid & 63) == 0) wsum[tid >> 6] = ss;
    __syncthreads();
    if (tid == 0)
        partials[bx + 8 * (by + 8 * b)] = (wsum[0] + wsum[1]) + (wsum[2] + wsum[3]);
}

// Phase 2 (reduce fused): each block sums the 1024 partials itself (4 KB,
// L2-resident), then masks its 4096-element slice: mask = (ratio > 1/sqrt(ss)).
__global__ __launch_bounds__(256) void li_phase2(
    const float* __restrict__ partials, float* __restrict__ io)
{
    __shared__ float wsum[4];
    __shared__ float s_inv;
    const int tid = threadIdx.x;

    float s = 0.f;
#pragma unroll
    for (int i = 0; i < NBLK / 256; i++)
        s += partials[tid + i * 256];
#pragma unroll
    for (int off = 32; off > 0; off >>= 1)
        s += __shfl_down(s, off, 64);
    if ((tid & 63) == 0) wsum[tid >> 6] = s;
    __syncthreads();
    if (tid == 0)
        s_inv = 1.0f / sqrtf((wsum[0] + wsum[1]) + (wsum[2] + wsum[3]));
    __syncthreads();

    const float inv = s_inv;
    const int base = blockIdx.x * 4096 + tid * 4;
#pragma unroll
    for (int k = 0; k < 4; k++) {
        const int i = base + k * 1024;
        float4 r = *(const float4*)(io + i);
        float4 m;
        m.x = (r.x > inv) ? 1.f : 0.f;
        m.y = (r.y > inv) ? 1.f : 0.f;
        m.z = (r.z > inv) ? 1.f : 0.f;
        m.w = (r.w > inv) ? 1.f : 0.f;
        *(float4*)(io + i) = m;
    }
}

extern "C" void kernel_launch(void* const* d_in, const int* in_sizes, int n_in,
                              void* d_out, int out_size, void* d_ws, size_t ws_size,
                              hipStream_t stream) {
    const float* x  = (const float*)d_in[0];
    const float* kw = (const float*)d_in[1];
    float* out   = (float*)d_out;
    float* ratio = out;                       // becomes mask after phase 2
    float* avg   = out + N_PIX;
    float* dif   = out + 2 * (size_t)N_PIX;
    float* ws    = (float*)d_ws;              // [0,NBLK): partials (fully written)

    dim3 g(HW / TX, HW / TY, NB);   // 8 x 8 x 16 = 1024 blocks
    li_phase1<<<g, 256, 0, stream>>>(x, kw, ratio, avg, dif, ws);
    li_phase2<<<N_PIX / 4096, 256, 0, stream>>>(ws, ratio);
}